// Round 4
// baseline (491.698 us; speedup 1.0000x reference)
//
#include <hip/hip_runtime.h>
#include <hip/hip_bf16.h>
#include <math.h>

typedef unsigned short u16;
typedef unsigned int u32;
typedef short s16x8 __attribute__((ext_vector_type(8)));
typedef unsigned short u16x8 __attribute__((ext_vector_type(8)));
typedef float f32x4 __attribute__((ext_vector_type(4)));

// Problem constants
#define TTOK 2048
#define HDIM 2048
#define ENUM 32
#define IDIM 768
#define KTOP 4

// Workspace layout (bytes)
#define WS_XB   0L                         // u16[2048*2048]  x in bf16       (8 MB)
#define WS_ACT  8388608L                   // u16[8192*768]   act bf16        (12.6 MB)
#define WS_TIDX 20971520L                  // int[8192] topk expert idx
#define WS_TW   (WS_TIDX + 32768L)         // float[8192] topk weights
#define WS_CNT  (WS_TW + 32768L)           // int[32] counts
#define WS_OFFS (WS_CNT + 128L)            // int[33] offsets
#define WS_CUR  (WS_OFFS + 256L)           // int[32] cursors
#define WS_RTOK (WS_CUR + 128L)            // int[8192] row -> token
#define WS_RW   (WS_RTOK + 32768L)         // float[8192] row -> routing weight

// LDS row stride: 40 u16 = 80B = 20 dwords. All b128 accesses 16B-aligned;
// stride-20-dword rows tile the 8 four-bank groups uniformly (8 lanes/group
// per b128 = structural minimum, conflict-free).
#define LDAU 40

__device__ __forceinline__ u16 f2bf(float f) {
  unsigned u = __builtin_bit_cast(unsigned, f);
  unsigned r = (u + 0x7fffu + ((u >> 16) & 1u)) >> 16;
  return (u16)r;
}
__device__ __forceinline__ unsigned pk2(float a, float b) {
  return (unsigned)f2bf(a) | ((unsigned)f2bf(b) << 16);
}

// ---------------- x f32 -> bf16 ----------------
__global__ __launch_bounds__(256) void cvt_x_kernel(const float* __restrict__ x,
                                                    u16* __restrict__ xb) {
  long i = ((long)blockIdx.x * 256 + threadIdx.x) * 8;
  float4 a = *(const float4*)(x + i);
  float4 b = *(const float4*)(x + i + 4);
  uint4 o;
  o.x = pk2(a.x, a.y);
  o.y = pk2(a.z, a.w);
  o.z = pk2(b.x, b.y);
  o.w = pk2(b.z, b.w);
  *(uint4*)(xb + i) = o;
}

// ---------------- router ----------------
__global__ __launch_bounds__(256) void router_kernel(const float* __restrict__ x,
                                                     const float* __restrict__ gw,
                                                     int* __restrict__ tidx,
                                                     float* __restrict__ tw,
                                                     int* __restrict__ counts) {
  __shared__ float xs[HDIM];
  __shared__ float part[256];
  __shared__ float lg[ENUM];
  int t = blockIdx.x;
  const float4* xr = (const float4*)(x + (long)t * HDIM);
  float4* xs4 = (float4*)xs;
  for (int i = threadIdx.x; i < HDIM / 4; i += 256) xs4[i] = xr[i];
  __syncthreads();
  int e = threadIdx.x >> 3, ch = threadIdx.x & 7;
  const float4* gp = (const float4*)(gw + (long)e * HDIM + ch * 256);
  const float4* xp = (const float4*)(xs + ch * 256);
  float s = 0.f;
#pragma unroll 8
  for (int c = 0; c < 64; c++) {
    float4 gv = gp[c], xv = xp[c];
    s += gv.x * xv.x + gv.y * xv.y + gv.z * xv.z + gv.w * xv.w;
  }
  part[threadIdx.x] = s;
  __syncthreads();
  if (threadIdx.x < 32) {
    float v = 0.f;
#pragma unroll
    for (int j = 0; j < 8; j++) v += part[threadIdx.x * 8 + j];
    lg[threadIdx.x] = v;
  }
  __syncthreads();
  if (threadIdx.x == 0) {
    int sel[KTOP]; float sv[KTOP];
    unsigned mask = 0;
    for (int k = 0; k < KTOP; k++) {
      float best = -INFINITY; int bi = 0;
      for (int j = 0; j < ENUM; j++)
        if (!((mask >> j) & 1u) && lg[j] > best) { best = lg[j]; bi = j; }
      mask |= 1u << bi; sel[k] = bi; sv[k] = best;
    }
    float m = sv[0], den = 0.f, ex[KTOP];
    for (int k = 0; k < KTOP; k++) { ex[k] = expf(sv[k] - m); den += ex[k]; }
    for (int k = 0; k < KTOP; k++) {
      tidx[t * KTOP + k] = sel[k];
      tw[t * KTOP + k] = ex[k] / den;
      atomicAdd(&counts[sel[k]], 1);
    }
  }
}

// ---------------- scan ----------------
__global__ void scan_kernel(const int* __restrict__ counts, int* __restrict__ offs,
                            int* __restrict__ cur) {
  if (threadIdx.x == 0) {
    int a = 0;
    for (int e = 0; e < ENUM; e++) { offs[e] = a; a += counts[e]; }
    offs[ENUM] = a;
  }
  if (threadIdx.x < ENUM) cur[threadIdx.x] = 0;
}

// ---------------- scatter ----------------
__global__ __launch_bounds__(256) void scatter_kernel(const int* __restrict__ tidx,
                                                      const float* __restrict__ tw,
                                                      const int* __restrict__ offs,
                                                      int* __restrict__ cur,
                                                      int* __restrict__ rtok,
                                                      float* __restrict__ rw) {
  int i = blockIdx.x * 256 + threadIdx.x;
  int e = tidx[i];
  int pos = atomicAdd(&cur[e], 1);
  int row = offs[e] + pos;
  rtok[row] = i >> 2;
  rw[row] = tw[i];
}

// ================= GEMM1: act = silu(x Wg) * (x Wu) =================
// BM=256, BN=32, BK=32, 512 threads (8 waves, each 32 rows x 32 cols).
// Double-buffered LDS, reg-staged pipeline. B transposed in LDS with
// lanes-along-K writes (conflict-free).
__global__ __launch_bounds__(512, 6) void gemm1_kernel(const u16* __restrict__ xb,
                                                       const float* __restrict__ wgp,
                                                       const float* __restrict__ wup,
                                                       const int* __restrict__ offs,
                                                       const int* __restrict__ rtok,
                                                       u16* __restrict__ act) {
  int d = blockIdx.x;
  int q8 = gridDim.x >> 3;
  int w = (d & 7) * q8 + (d >> 3);
  int nt = w % 24; int rem = w / 24; int mt = rem & 7; int e = rem >> 3;
  int off = offs[e], cnt = offs[e + 1] - off;
  int m0 = mt << 8;
  if (m0 >= cnt) return;
  int rows = cnt - m0; if (rows > 256) rows = 256;
  int baser = off + m0;
  int n0 = nt << 5;

  __shared__ __align__(16) u16 As[2][256 * LDAU];     // 40 KB
  __shared__ __align__(16) u16 Bs[2][2][32 * LDAU];   // 10 KB

  int tid = threadIdx.x;
  int ln = tid & 63;
  int wv = tid >> 6;
  int lhi = ln >> 4, llo = ln & 15;

  // ---- A staging: 2 threads/row, 16 u16 (32B) each ----
  int ar = tid >> 1;
  int kcA = (tid & 1) * 16;
  int arow = ar < rows ? ar : rows - 1;
  const u16* aSrc = xb + (long)rtok[baser + arow] * HDIM + kcA;
  u16* aDst0 = &As[0][ar * LDAU + kcA];
  u16* aDst1 = &As[1][ar * LDAU + kcA];

  // ---- B staging: lanes along K. 128 threads per matrix.
  // gate: tid 0..127 (waves 0,1); up: tid 256..383 (waves 4,5).
  int isB = ((tid & 255) < 128);
  int mat = tid >> 8;                 // 0=gate, 1=up (when isB)
  int t2 = tid & 127;
  int qk = t2 & 15;                   // k-pair index: k = 2qk, 2qk+1
  int gg = t2 >> 4;                   // n-chunk 0..7 -> cols 4gg..4gg+3
  const float* bSrc = (mat ? wup : wgp) + (long)e * (HDIM * IDIM) +
                      (long)(2 * qk) * IDIM + n0 + 4 * gg;
  u16* bDst0 = &Bs[0][mat][4 * gg * LDAU + qk * 2];
  u16* bDst1 = &Bs[1][mat][4 * gg * LDAU + qk * 2];

  f32x4 accg[2][2], accu[2][2];
  f32x4 zz = {0.f, 0.f, 0.f, 0.f};
#pragma unroll
  for (int a = 0; a < 2; a++)
#pragma unroll
    for (int b = 0; b < 2; b++) { accg[a][b] = zz; accu[a][b] = zz; }

  u16x8 rA0, rA1;
  float4 rB0, rB1;

#define G1_LOAD(t)                                                   \
  {                                                                  \
    const u16* ap = aSrc + (t) * 32;                                 \
    rA0 = *(const u16x8*)ap;                                         \
    rA1 = *(const u16x8*)(ap + 8);                                   \
    if (isB) {                                                       \
      const float* bp = bSrc + (long)(t) * 32 * IDIM;                \
      rB0 = *(const float4*)bp;                                      \
      rB1 = *(const float4*)(bp + IDIM);                             \
    }                                                                \
  }
#define G1_WRITE(buf)                                                \
  {                                                                  \
    u16* ad = buf ? aDst1 : aDst0;                                   \
    *(u16x8*)ad = rA0;                                               \
    *(u16x8*)(ad + 8) = rA1;                                         \
    if (isB) {                                                       \
      u16* bd = buf ? bDst1 : bDst0;                                 \
      *(u32*)(bd + 0 * LDAU) = pk2(rB0.x, rB1.x);                    \
      *(u32*)(bd + 1 * LDAU) = pk2(rB0.y, rB1.y);                    \
      *(u32*)(bd + 2 * LDAU) = pk2(rB0.z, rB1.z);                    \
      *(u32*)(bd + 3 * LDAU) = pk2(rB0.w, rB1.w);                    \
    }                                                                \
  }

  const int NS = HDIM / 32;  // 64
  G1_LOAD(0);
  G1_WRITE(0);
  G1_LOAD(1);
  __syncthreads();

  for (int t = 0; t < NS; ++t) {
    int cur = t & 1;
    if (t + 1 < NS) G1_WRITE(cur ^ 1);
    if (t + 2 < NS) G1_LOAD(t + 2);
    {
      const u16* Ab = As[cur];
      const u16* Bg = Bs[cur][0];
      const u16* Bu = Bs[cur][1];
      s16x8 a[2];
#pragma unroll
      for (int mf = 0; mf < 2; mf++) {
        int r = wv * 32 + mf * 16 + llo;
        a[mf] = *(const s16x8*)&Ab[r * LDAU + lhi * 8];
      }
#pragma unroll
      for (int nf = 0; nf < 2; nf++) {
        int c = nf * 16 + llo;
        s16x8 bg = *(const s16x8*)&Bg[c * LDAU + lhi * 8];
        s16x8 bu = *(const s16x8*)&Bu[c * LDAU + lhi * 8];
#pragma unroll
        for (int mf = 0; mf < 2; mf++) {
          accg[mf][nf] = __builtin_amdgcn_mfma_f32_16x16x32_bf16(a[mf], bg, accg[mf][nf], 0, 0, 0);
          accu[mf][nf] = __builtin_amdgcn_mfma_f32_16x16x32_bf16(a[mf], bu, accu[mf][nf], 0, 0, 0);
        }
      }
    }
    __syncthreads();
  }

  // epilogue: silu(g)*u -> bf16 act
  int rbase = wv * 32 + lhi * 4;
  int cbase = n0 + llo;
#pragma unroll
  for (int mf = 0; mf < 2; mf++) {
#pragma unroll
    for (int r4 = 0; r4 < 4; r4++) {
      int rl = rbase + mf * 16 + r4;
      if (rl < rows) {
        long rowb = (long)(baser + rl) * IDIM;
#pragma unroll
        for (int nf = 0; nf < 2; nf++) {
          float g = accg[mf][nf][r4], u = accu[mf][nf][r4];
          float av = g / (1.f + __expf(-g)) * u;
          act[rowb + cbase + nf * 16] = f2bf(av);
        }
      }
    }
  }
#undef G1_LOAD
#undef G1_WRITE
}

// ================= GEMM2: out[tok] += w * (act Wd) =================
// BM=256, BN=64, BK=32, 512 threads (8 waves, each 32 rows x 64 cols).
__global__ __launch_bounds__(512, 6) void gemm2_kernel(const u16* __restrict__ act,
                                                       const float* __restrict__ wdp,
                                                       const int* __restrict__ offs,
                                                       const int* __restrict__ rtok,
                                                       const float* __restrict__ rw,
                                                       float* __restrict__ out) {
  int d = blockIdx.x;
  int q8 = gridDim.x >> 3;
  int w = (d & 7) * q8 + (d >> 3);
  int nt = w & 31; int mt = (w >> 5) & 7; int e = w >> 8;
  int off = offs[e], cnt = offs[e + 1] - off;
  int m0 = mt << 8;
  if (m0 >= cnt) return;
  int rows = cnt - m0; if (rows > 256) rows = 256;
  int baser = off + m0;
  int n0 = nt << 6;

  __shared__ __align__(16) u16 As[2][256 * LDAU];   // 40 KB
  __shared__ __align__(16) u16 Bs[2][64 * LDAU];    // 10 KB

  int tid = threadIdx.x;
  int ln = tid & 63;
  int wv = tid >> 6;
  int lhi = ln >> 4, llo = ln & 15;

  int ar = tid >> 1;
  int kcA = (tid & 1) * 16;
  int arow = ar < rows ? ar : rows - 1;
  const u16* aSrc = act + (long)(baser + arow) * IDIM + kcA;
  u16* aDst0 = &As[0][ar * LDAU + kcA];
  u16* aDst1 = &As[1][ar * LDAU + kcA];

  // B: 256 threads (waves 0..3), lanes along K
  int isB = (tid < 256);
  int qk = tid & 15;
  int gg = (tid >> 4) & 15;           // 0..15 -> cols 4gg..4gg+3
  const float* bSrc = wdp + (long)e * (IDIM * HDIM) + (long)(2 * qk) * HDIM + n0 + 4 * gg;
  u16* bDst0 = &Bs[0][4 * gg * LDAU + qk * 2];
  u16* bDst1 = &Bs[1][4 * gg * LDAU + qk * 2];

  f32x4 acc[2][4];
  f32x4 zz = {0.f, 0.f, 0.f, 0.f};
#pragma unroll
  for (int a = 0; a < 2; a++)
#pragma unroll
    for (int b = 0; b < 4; b++) acc[a][b] = zz;

  u16x8 rA0, rA1;
  float4 rB0, rB1;

#define G2_LOAD(t)                                                   \
  {                                                                  \
    const u16* ap = aSrc + (t) * 32;                                 \
    rA0 = *(const u16x8*)ap;                                         \
    rA1 = *(const u16x8*)(ap + 8);                                   \
    if (isB) {                                                       \
      const float* bp = bSrc + (long)(t) * 32 * HDIM;                \
      rB0 = *(const float4*)bp;                                      \
      rB1 = *(const float4*)(bp + HDIM);                             \
    }                                                                \
  }
#define G2_WRITE(buf)                                                \
  {                                                                  \
    u16* ad = buf ? aDst1 : aDst0;                                   \
    *(u16x8*)ad = rA0;                                               \
    *(u16x8*)(ad + 8) = rA1;                                         \
    if (isB) {                                                       \
      u16* bd = buf ? bDst1 : bDst0;                                 \
      *(u32*)(bd + 0 * LDAU) = pk2(rB0.x, rB1.x);                    \
      *(u32*)(bd + 1 * LDAU) = pk2(rB0.y, rB1.y);                    \
      *(u32*)(bd + 2 * LDAU) = pk2(rB0.z, rB1.z);                    \
      *(u32*)(bd + 3 * LDAU) = pk2(rB0.w, rB1.w);                    \
    }                                                                \
  }

  const int NS = IDIM / 32;  // 24
  G2_LOAD(0);
  G2_WRITE(0);
  G2_LOAD(1);
  __syncthreads();

  for (int t = 0; t < NS; ++t) {
    int cur = t & 1;
    if (t + 1 < NS) G2_WRITE(cur ^ 1);
    if (t + 2 < NS) G2_LOAD(t + 2);
    {
      const u16* Ab = As[cur];
      const u16* Bb = Bs[cur];
      s16x8 a[2];
#pragma unroll
      for (int mf = 0; mf < 2; mf++) {
        int r = wv * 32 + mf * 16 + llo;
        a[mf] = *(const s16x8*)&Ab[r * LDAU + lhi * 8];
      }
#pragma unroll
      for (int nf = 0; nf < 4; nf++) {
        int c = nf * 16 + llo;
        s16x8 bv = *(const s16x8*)&Bb[c * LDAU + lhi * 8];
#pragma unroll
        for (int mf = 0; mf < 2; mf++)
          acc[mf][nf] = __builtin_amdgcn_mfma_f32_16x16x32_bf16(a[mf], bv, acc[mf][nf], 0, 0, 0);
      }
    }
    __syncthreads();
  }

  // epilogue: scale by routing weight, atomic add into out
  int rbase = wv * 32 + lhi * 4;
  int cbase = n0 + llo;
#pragma unroll
  for (int mf = 0; mf < 2; mf++) {
#pragma unroll
    for (int r4 = 0; r4 < 4; r4++) {
      int rl = rbase + mf * 16 + r4;
      if (rl < rows) {
        int rr = baser + rl;
        float wt = rw[rr];
        long ob = (long)rtok[rr] * HDIM + cbase;
#pragma unroll
        for (int nf = 0; nf < 4; nf++)
          atomicAdd(&out[ob + nf * 16], acc[mf][nf][r4] * wt);
      }
    }
  }
#undef G2_LOAD
#undef G2_WRITE
}

extern "C" void kernel_launch(void* const* d_in, const int* in_sizes, int n_in,
                              void* d_out, int out_size, void* d_ws, size_t ws_size,
                              hipStream_t stream) {
  const float* x = (const float*)d_in[0];
  const float* gw = (const float*)d_in[1];
  const float* wgate = (const float*)d_in[2];
  const float* wup = (const float*)d_in[3];
  const float* wdown = (const float*)d_in[4];
  float* out = (float*)d_out;

  char* ws = (char*)d_ws;
  u16* xb = (u16*)(ws + WS_XB);
  u16* act = (u16*)(ws + WS_ACT);
  int* tidx = (int*)(ws + WS_TIDX);
  float* tw = (float*)(ws + WS_TW);
  int* cnt = (int*)(ws + WS_CNT);
  int* offs = (int*)(ws + WS_OFFS);
  int* cur = (int*)(ws + WS_CUR);
  int* rtok = (int*)(ws + WS_RTOK);
  float* rw = (float*)(ws + WS_RW);

  hipMemsetAsync(cnt, 0, 128, stream);
  hipMemsetAsync(d_out, 0, (size_t)out_size * sizeof(float), stream);

  hipLaunchKernelGGL(cvt_x_kernel, dim3(TTOK * HDIM / (256 * 8)), dim3(256), 0, stream, x, xb);
  hipLaunchKernelGGL(router_kernel, dim3(TTOK), dim3(256), 0, stream, x, gw, tidx, tw, cnt);
  hipLaunchKernelGGL(scan_kernel, dim3(1), dim3(64), 0, stream, cnt, offs, cur);
  hipLaunchKernelGGL(scatter_kernel, dim3(TTOK * KTOP / 256), dim3(256), 0, stream, tidx, tw, offs, cur, rtok, rw);
  hipLaunchKernelGGL(gemm1_kernel, dim3(ENUM * 8 * 24), dim3(512), 0, stream, xb, wgate, wup, offs, rtok, act);
  hipLaunchKernelGGL(gemm2_kernel, dim3(ENUM * 8 * 32), dim3(512), 0, stream, act, wdown, offs, rtok, rw, out);
}